// Round 6
// baseline (344.738 us; speedup 1.0000x reference)
//
#include <hip/hip_runtime.h>

typedef short s8_t __attribute__((ext_vector_type(8)));
typedef float f4_t __attribute__((ext_vector_type(4)));

// ======================= compile-time Clebsch-Gordan =======================
namespace cgc {

struct Cx { double re, im; };

constexpr double FACT[13] = {1.,1.,2.,6.,24.,120.,720.,5040.,40320.,362880.,
                             3628800.,39916800.,479001600.};

constexpr double cfabs(double x){ return x < 0 ? -x : x; }

constexpr double csqrt(double x){
  if (x <= 0) return 0;
  double g = x > 1 ? x : 1.0;
  for (int i = 0; i < 80; ++i){
    double ng = 0.5*(g + x/g);
    if (ng == g) break;
    g = ng;
  }
  return g;
}

constexpr int imax3(int a,int b,int c){ int m=a; if(b>m)m=b; if(c>m)m=c; return m; }
constexpr int imin3(int a,int b,int c){ int m=a; if(b<m)m=b; if(c<m)m=c; return m; }

constexpr double clebsch(int j1,int m1,int j2,int m2,int j3,int m3){
  if (m1 + m2 != m3) return 0;
  const int jmin = j1 > j2 ? j1 - j2 : j2 - j1;
  if (j3 < jmin || j3 > j1 + j2) return 0;
  if (m1 < -j1 || m1 > j1 || m2 < -j2 || m2 > j2 || m3 < -j3 || m3 > j3) return 0;
  double pref = csqrt((2*j3+1)*FACT[j3+j1-j2]*FACT[j3-j1+j2]*FACT[j1+j2-j3]/FACT[j1+j2+j3+1]);
  pref *= csqrt(FACT[j3+m3]*FACT[j3-m3]*FACT[j1-m1]*FACT[j1+m1]*FACT[j2-m2]*FACT[j2+m2]);
  const int kmin = imax3(0, j2-j3-m1, j1-j3+m2);
  const int kmax = imin3(j1+j2-j3, j1-m1, j2+m2);
  double s = 0;
  for (int k = kmin; k <= kmax; ++k){
    double d = FACT[k]*FACT[j1+j2-j3-k]*FACT[j1-m1-k]*FACT[j2+m2-k]
             * FACT[j3-j2+m1+k]*FACT[j3-j1-m2+k];
    s += ((k & 1) ? -1.0 : 1.0) / d;
  }
  return pref * s;
}

constexpr Cx cmul(Cx a, Cx b){ return Cx{a.re*b.re - a.im*b.im, a.re*b.im + a.im*b.re}; }

// U[l+mr][l+mc] of the complex->real SH transform (row: real m, col: complex m)
constexpr Cx Uc2r(int mr, int mc){
  const double s2i = 0.70710678118654752440;
  if (mr == 0) return (mc == 0) ? Cx{1.,0.} : Cx{0.,0.};
  if (mr > 0){
    if (mc ==  mr) return Cx{ (mr & 1) ? -s2i : s2i, 0. };
    if (mc == -mr) return Cx{ s2i, 0. };
    return Cx{0.,0.};
  }
  const int m = -mr;
  if (mc ==  m) return Cx{0., (m & 1) ?  s2i : -s2i };
  if (mc == -m) return Cx{0., s2i };
  return Cx{0.,0.};
}

template<int L1,int L2,int L3>
struct CArr { float v[(2*L1+1)*(2*L2+1)*(2*L3+1)]; };

template<int L1,int L2,int L3>
constexpr CArr<L1,L2,L3> buildCG(){
  constexpr int D1 = 2*L1+1, D2 = 2*L2+1, D3 = 2*L3+1;
  // complex-basis CG cached once per coupling (m3 = m1+m2 enforced)
  double cgd[D1*D2] = {};
  for (int i = 0; i < D1; ++i)
    for (int j = 0; j < D2; ++j){
      const int m1c = i - L1, m2c = j - L2, m3c = m1c + m2c;
      cgd[i*D2+j] = (m3c < -L3 || m3c > L3) ? 0.0 : clebsch(L1,m1c,L2,m2c,L3,m3c);
    }
  double tre[D1*D2*D3] = {};
  double tim[D1*D2*D3] = {};
  for (int a = 0; a < D1; ++a)
  for (int b = 0; b < D2; ++b)
  for (int c = 0; c < D3; ++c){
    const int m1r = a - L1, m2r = b - L2, m3r = c - L3;
    double sre = 0, sim = 0;
    const int n1 = (m1r == 0) ? 1 : 2;
    const int n2 = (m2r == 0) ? 1 : 2;
    for (int ii = 0; ii < n1; ++ii)
    for (int jj = 0; jj < n2; ++jj){
      const int m1c = ii ? -m1r : m1r;
      const int m2c = jj ? -m2r : m2r;
      const int m3c = m1c + m2c;
      if (m3c < -L3 || m3c > L3) continue;
      const Cx u3 = Uc2r(m3r, m3c);
      if (u3.re == 0 && u3.im == 0) continue;
      const double cgv = cgd[(L1+m1c)*D2 + (L2+m2c)];
      if (cgv == 0) continue;
      const Cx u1 = Uc2r(m1r, m1c);
      const Cx u2 = Uc2r(m2r, m2c);
      const Cx p  = cmul(u1, u2);
      const Cx t  = cmul(p, Cx{u3.re, -u3.im});   // conj(U3)
      sre += t.re * cgv;
      sim += t.im * cgv;
    }
    tre[(a*D2+b)*D3+c] = sre;
    tim[(a*D2+b)*D3+c] = sim;
  }
  // tensor is purely real or purely imaginary; pick like the reference
  double mre = 0, mim = 0;
  for (int k = 0; k < D1*D2*D3; ++k){
    if (cfabs(tre[k]) > mre) mre = cfabs(tre[k]);
    if (cfabs(tim[k]) > mim) mim = cfabs(tim[k]);
  }
  CArr<L1,L2,L3> o{};
  for (int k = 0; k < D1*D2*D3; ++k)
    o.v[k] = (float)((mre >= mim) ? tre[k] : tim[k]);
  return o;
}

template<int L1,int L2,int L3>
constexpr CArr<L1,L2,L3> CG_V = buildCG<L1,L2,L3>();

constexpr int lminf(int a,int b){ return a > b ? a - b : b - a; }
constexpr int lmaxf(int a,int b){ return (a + b < 4) ? (a + b) : 4; }
constexpr int cplIndex(int l1,int l2,int lo){
  int idx = 0;
  for (int a = 0; a <= 3; ++a)
    for (int b = 0; b <= 3; ++b){
      const int c0 = lminf(a,b), c1 = lmaxf(a,b);
      for (int c = c0; c <= c1; ++c){
        if (a == l1 && b == l2 && c == lo) return idx;
        ++idx;
      }
    }
  return -1;
}
constexpr int poff(int l1,int l2,int lo){
  int s = 0;
  for (int c = lminf(l1,l2); c < lo; ++c) s += 2*c + 1;
  return s;
}
constexpr int psize(int l1,int l2){ return poff(l1, l2, lmaxf(l1,l2) + 1); }

// first pq index (in P-major execution order) whose cg for slot (LO,M) is
// nonzero -> that FMA becomes a plain mul (kills the part[] zero-init movs)
template<int L1,int L2,int LO>
constexpr int firstPQv(int M){
  const int NPQ = (2*L1+1)*(2*L2+1);
  for (int pq = 0; pq < NPQ; ++pq){
    const float v = CG_V<L1,L2,LO>.v[pq*(2*LO+1)+M];
    if (v > 1e-7f || v < -1e-7f) return pq;
  }
  return -1;
}
// is (l1,l2) the first group (row-major execution order) coupling into lo?
constexpr bool isAccFirst(int l1,int l2,int lo){
  for (int a = 0; a <= 3; ++a)
    for (int b = 0; b <= 3; ++b)
      if (lminf(a,b) <= lo && lo <= lmaxf(a,b))
        return (a == l1) && (b == l2);
  return false;
}

} // namespace cgc

// ======================= device helpers =======================
__device__ __forceinline__ unsigned short f2bf(float x){
  unsigned u = __float_as_uint(x);
  u += 0x7fffu + ((u >> 16) & 1u);       // RNE
  return (unsigned short)(u >> 16);
}

// W pre-packed into bf16 MFMA B-fragment order: [i][ntile][kstep][lane][8]
__device__ __attribute__((aligned(16))) unsigned short WF[81920];

// per-thread radial-filter values: 40 bf16 packed in 20 dwords (5x ds_read_b128)
struct FU { unsigned u[20]; };

template<int I>
__device__ __forceinline__ float getF(const FU& f){
  const unsigned w = f.u[I >> 1];
  return __uint_as_float((I & 1) ? (w & 0xffff0000u) : (w << 16));
}

// ---- CG accumulation: ALL indices template params -> literal coefficients,
// zeros deleted, first touch per slot is a write (no zero-init). ----
template<int L1,int L2,int PQ,int LO,int LMAX,int M>
struct EmitM {
  static __device__ __forceinline__ void run(float t, float* __restrict__ part){
    constexpr float cg = cgc::CG_V<L1,L2,LO>.v[PQ*(2*LO+1) + M];
    if constexpr (cg > 1e-7f || cg < -1e-7f){
      constexpr int off = cgc::poff(L1,L2,LO) + M;
      if constexpr (PQ == cgc::firstPQv<L1,L2,LO>(M))
        part[off] = cg * t;
      else
        part[off] = fmaf(cg, t, part[off]);
    }
    if constexpr (M + 1 < 2*LO + 1)
      EmitM<L1,L2,PQ,LO,LMAX,M+1>::run(t, part);
    else if constexpr (LO < LMAX)
      EmitM<L1,L2,PQ,LO+1,LMAX,0>::run(t, part);
  }
};

template<int L1,int L2,int P,int Q>
struct PQLoop {
  static __device__ __forceinline__ void run(const float* __restrict__ xr,
                                             const float* __restrict__ yr,
                                             float* __restrict__ part){
    const float t = xr[L1*L1 + P] * yr[L2*L2 + Q];
    EmitM<L1, L2, P*(2*L2+1)+Q, cgc::lminf(L1,L2), cgc::lmaxf(L1,L2), 0>::run(t, part);
    if constexpr (Q + 1 < 2*L2 + 1)
      PQLoop<L1,L2,P,Q+1>::run(xr, yr, part);
    else if constexpr (P + 1 < 2*L1 + 1)
      PQLoop<L1,L2,P+1,0>::run(xr, yr, part);
  }
};

template<int L1,int L2,int LO,int M>
struct ScaleM {
  static __device__ __forceinline__ void run(const float* __restrict__ part,
                                             float* __restrict__ acc, float fv){
    constexpr int s = LO*LO + M;
    constexpr bool touched = (cgc::firstPQv<L1,L2,LO>(M) != -1);
    if constexpr (cgc::isAccFirst(L1,L2,LO)){
      if constexpr (touched) acc[s] = fv * part[cgc::poff(L1,L2,LO) + M];
      else                   acc[s] = 0.f;
    } else if constexpr (touched){
      acc[s] = fmaf(fv, part[cgc::poff(L1,L2,LO) + M], acc[s]);
    }
    if constexpr (M + 1 < 2*LO + 1) ScaleM<L1,L2,LO,M+1>::run(part, acc, fv);
  }
};

template<int L1,int L2,int LO,int LMAX>
struct ScaleAccum {
  static __device__ __forceinline__ void run(const float* __restrict__ part,
                                             float* __restrict__ acc,
                                             const FU& fu){
    const float fv = getF<cgc::cplIndex(L1,L2,LO)>(fu);
    ScaleM<L1,L2,LO,0>::run(part, acc, fv);
    if constexpr (LO < LMAX) ScaleAccum<L1,L2,LO+1,LMAX>::run(part, acc, fu);
  }
};

template<int L1,int L2>
__device__ __forceinline__ void doGroup(const float* __restrict__ xr,
                                        const float* __restrict__ yr,
                                        float* __restrict__ acc,
                                        const FU& fu){
  float part[cgc::psize(L1,L2)];
  PQLoop<L1,L2,0,0>::run(xr, yr, part);
  ScaleAccum<L1,L2,cgc::lminf(L1,L2),cgc::lmaxf(L1,L2)>::run(part, acc, fu);
}

// ======================= kernels =======================
__global__ __launch_bounds__(256) void prep_wf(const float* __restrict__ W){
  const int idx = blockIdx.x*256 + threadIdx.x;         // 81920 total
  const int j = idx & 7;
  const int l = (idx >> 3) & 63;
  const int s = (idx >> 9) & 1;
  const int t = (idx >> 10) & 1;
  const int i = idx >> 11;
  const int k   = s*32 + ((l >> 4) << 3) + j;           // contiguous-8 k per lane
  const int col = (t << 4) + (l & 15);
  WF[idx] = f2bf(W[(i << 11) + (k << 5) + col]);
}

// Fm layout: n-major per edge row: u16 index = el*1280 + n*40 + i.
// -> phase-2 thread (el,n) reads its 40 f-values as 80 contiguous, 16B-aligned
//    bytes = 5x ds_read_b128.
// __launch_bounds__(512, 4): VGPR cap 128 (wave64 pool 512/SIMD).
// x/y prefetch via VOLATILE loads: LLVM cannot sink volatile loads across the
// barrier intrinsic or into phase 2, so the 64 loads enter the vmcnt queue
// FIRST. Phase-1's own vmcnt(N) waits (WF frags) drain these older loads as a
// side effect -> x/y HBM latency overlaps phase-1 load latency (MLP) instead
// of serializing at the barrier. (Rounds 4/5: non-volatile loads were sunk to
// the barrier/pin, VGPR=56/60 and latency fully exposed.)
__global__ __launch_bounds__(512, 4) void pairmix(const float* __restrict__ x,
                                                  const float* __restrict__ y,
                                                  const float* __restrict__ r,
                                                  float* __restrict__ out){
  __shared__ unsigned short Fm[16*1280];                // 40960 B
  const int e0   = blockIdx.x << 4;                     // 16 edges per block
  const int tid  = threadIdx.x;
  const int lane = tid & 63;
  const int wv   = tid >> 6;                            // 0..7

  // ---- Prefetch x/y (volatile: pinned at top, in flight under phase 1) ----
  const int n  = tid & 31;
  const int el = tid >> 5;                              // 0..15
  const volatile float* xp = x + (size_t)(e0 + el)*512 + n;
  const volatile float* yp = y + (size_t)(e0 + el)*512 + n;
  float xr_[16], yr_[16];
  #pragma unroll
  for (int s = 0; s < 16; ++s){ xr_[s] = xp[s << 5]; yr_[s] = yp[s << 5]; }
  __builtin_amdgcn_sched_barrier(0);                    // keep x/y oldest in vmcnt queue

  // ---- Phase 1: F = r @ W via bf16 MFMA (M=16 edges, N=1280, K=64) ----
  {
    const int mrow = lane & 15;                         // edge row
    const int kch  = (lane >> 4) << 3;                  // k chunk base
    const float* rp = r + (size_t)(e0 + mrow)*64 + kch;
    s8_t A[2];
    #pragma unroll
    for (int s = 0; s < 2; ++s){
      const float4 v0 = *(const float4*)(rp + s*32);
      const float4 v1 = *(const float4*)(rp + s*32 + 4);
      union { s8_t v; unsigned u[4]; } pk;
      pk.u[0] = (unsigned)f2bf(v0.x) | ((unsigned)f2bf(v0.y) << 16);
      pk.u[1] = (unsigned)f2bf(v0.z) | ((unsigned)f2bf(v0.w) << 16);
      pk.u[2] = (unsigned)f2bf(v1.x) | ((unsigned)f2bf(v1.y) << 16);
      pk.u[3] = (unsigned)f2bf(v1.z) | ((unsigned)f2bf(v1.w) << 16);
      A[s] = pk.v;
    }
    #pragma unroll
    for (int tt = 0; tt < 10; ++tt){                    // 8 waves x 10 = 80 tiles
      const int T  = wv*10 + tt;
      const int ci = T >> 1;                            // coupling 0..39
      const int th = T & 1;                             // n-half 0..1
      const s8_t B0 = *(const s8_t*)(WF + ((((ci*2 + th)*2 + 0)*64 + lane) << 3));
      const s8_t B1 = *(const s8_t*)(WF + ((((ci*2 + th)*2 + 1)*64 + lane) << 3));
      f4_t c = {0.f, 0.f, 0.f, 0.f};
      c = __builtin_amdgcn_mfma_f32_16x16x32_bf16(A[0], B0, c, 0, 0, 0);
      c = __builtin_amdgcn_mfma_f32_16x16x32_bf16(A[1], B1, c, 0, 0, 0);
      const int colN = th*16 + (lane & 15);             // channel n
      const int rb   = (lane >> 4) << 2;                // row-group base (edge)
      #pragma unroll
      for (int jj = 0; jj < 4; ++jj)
        Fm[(rb + jj)*1280 + colN*40 + ci] = f2bf(c[jj]); // C/D: col=lane&15, row=(lane>>4)*4+reg
    }
  }
  __syncthreads();

  // ---- Phase 2: CG contraction, one thread per (edge, channel) ----
  FU fu;
  const unsigned short* fB = &Fm[el*1280 + n*40];
  #pragma unroll
  for (int j = 0; j < 5; ++j)
    ((s8_t*)fu.u)[j] = *(const s8_t*)(fB + j*8);

  float acc[25];                                        // first-touch-written, no init

  doGroup<0,0>(xr_, yr_, acc, fu);
  doGroup<0,1>(xr_, yr_, acc, fu);
  doGroup<0,2>(xr_, yr_, acc, fu);
  doGroup<0,3>(xr_, yr_, acc, fu);
  doGroup<1,0>(xr_, yr_, acc, fu);
  doGroup<1,1>(xr_, yr_, acc, fu);
  doGroup<1,2>(xr_, yr_, acc, fu);
  doGroup<1,3>(xr_, yr_, acc, fu);
  doGroup<2,0>(xr_, yr_, acc, fu);
  doGroup<2,1>(xr_, yr_, acc, fu);
  doGroup<2,2>(xr_, yr_, acc, fu);
  doGroup<2,3>(xr_, yr_, acc, fu);
  doGroup<3,0>(xr_, yr_, acc, fu);
  doGroup<3,1>(xr_, yr_, acc, fu);
  doGroup<3,2>(xr_, yr_, acc, fu);
  doGroup<3,3>(xr_, yr_, acc, fu);

  float* op = out + (size_t)(e0 + el)*800 + n;
  #pragma unroll
  for (int s = 0; s < 25; ++s) op[s << 5] = acc[s];
}

// ======================= launch =======================
extern "C" void kernel_launch(void* const* d_in, const int* in_sizes, int n_in,
                              void* d_out, int out_size, void* d_ws, size_t ws_size,
                              hipStream_t stream){
  const float* x = (const float*)d_in[0];
  const float* y = (const float*)d_in[1];
  const float* r = (const float*)d_in[2];
  const float* W = (const float*)d_in[3];
  float* out = (float*)d_out;

  const int E = in_sizes[0] / 512;                      // 100000

  prep_wf<<<320, 256, 0, stream>>>(W);                  // 81920 threads
  pairmix<<<E / 16, 512, 0, stream>>>(x, y, r, out);
}

// Round 7
// 235.468 us; speedup vs baseline: 1.4641x; 1.4641x over previous
//
#include <hip/hip_runtime.h>

typedef short s8_t __attribute__((ext_vector_type(8)));
typedef float f4_t __attribute__((ext_vector_type(4)));

// ======================= compile-time Clebsch-Gordan =======================
namespace cgc {

struct Cx { double re, im; };

constexpr double FACT[13] = {1.,1.,2.,6.,24.,120.,720.,5040.,40320.,362880.,
                             3628800.,39916800.,479001600.};

constexpr double cfabs(double x){ return x < 0 ? -x : x; }

constexpr double csqrt(double x){
  if (x <= 0) return 0;
  double g = x > 1 ? x : 1.0;
  for (int i = 0; i < 80; ++i){
    double ng = 0.5*(g + x/g);
    if (ng == g) break;
    g = ng;
  }
  return g;
}

constexpr int imax3(int a,int b,int c){ int m=a; if(b>m)m=b; if(c>m)m=c; return m; }
constexpr int imin3(int a,int b,int c){ int m=a; if(b<m)m=b; if(c<m)m=c; return m; }

constexpr double clebsch(int j1,int m1,int j2,int m2,int j3,int m3){
  if (m1 + m2 != m3) return 0;
  const int jmin = j1 > j2 ? j1 - j2 : j2 - j1;
  if (j3 < jmin || j3 > j1 + j2) return 0;
  if (m1 < -j1 || m1 > j1 || m2 < -j2 || m2 > j2 || m3 < -j3 || m3 > j3) return 0;
  double pref = csqrt((2*j3+1)*FACT[j3+j1-j2]*FACT[j3-j1+j2]*FACT[j1+j2-j3]/FACT[j1+j2+j3+1]);
  pref *= csqrt(FACT[j3+m3]*FACT[j3-m3]*FACT[j1-m1]*FACT[j1+m1]*FACT[j2-m2]*FACT[j2+m2]);
  const int kmin = imax3(0, j2-j3-m1, j1-j3+m2);
  const int kmax = imin3(j1+j2-j3, j1-m1, j2+m2);
  double s = 0;
  for (int k = kmin; k <= kmax; ++k){
    double d = FACT[k]*FACT[j1+j2-j3-k]*FACT[j1-m1-k]*FACT[j2+m2-k]
             * FACT[j3-j2+m1+k]*FACT[j3-j1-m2+k];
    s += ((k & 1) ? -1.0 : 1.0) / d;
  }
  return pref * s;
}

constexpr Cx cmul(Cx a, Cx b){ return Cx{a.re*b.re - a.im*b.im, a.re*b.im + a.im*b.re}; }

// U[l+mr][l+mc] of the complex->real SH transform (row: real m, col: complex m)
constexpr Cx Uc2r(int mr, int mc){
  const double s2i = 0.70710678118654752440;
  if (mr == 0) return (mc == 0) ? Cx{1.,0.} : Cx{0.,0.};
  if (mr > 0){
    if (mc ==  mr) return Cx{ (mr & 1) ? -s2i : s2i, 0. };
    if (mc == -mr) return Cx{ s2i, 0. };
    return Cx{0.,0.};
  }
  const int m = -mr;
  if (mc ==  m) return Cx{0., (m & 1) ?  s2i : -s2i };
  if (mc == -m) return Cx{0., s2i };
  return Cx{0.,0.};
}

template<int L1,int L2,int L3>
struct CArr { float v[(2*L1+1)*(2*L2+1)*(2*L3+1)]; };

template<int L1,int L2,int L3>
constexpr CArr<L1,L2,L3> buildCG(){
  constexpr int D1 = 2*L1+1, D2 = 2*L2+1, D3 = 2*L3+1;
  // complex-basis CG cached once per coupling (m3 = m1+m2 enforced)
  double cgd[D1*D2] = {};
  for (int i = 0; i < D1; ++i)
    for (int j = 0; j < D2; ++j){
      const int m1c = i - L1, m2c = j - L2, m3c = m1c + m2c;
      cgd[i*D2+j] = (m3c < -L3 || m3c > L3) ? 0.0 : clebsch(L1,m1c,L2,m2c,L3,m3c);
    }
  double tre[D1*D2*D3] = {};
  double tim[D1*D2*D3] = {};
  for (int a = 0; a < D1; ++a)
  for (int b = 0; b < D2; ++b)
  for (int c = 0; c < D3; ++c){
    const int m1r = a - L1, m2r = b - L2, m3r = c - L3;
    double sre = 0, sim = 0;
    const int n1 = (m1r == 0) ? 1 : 2;
    const int n2 = (m2r == 0) ? 1 : 2;
    for (int ii = 0; ii < n1; ++ii)
    for (int jj = 0; jj < n2; ++jj){
      const int m1c = ii ? -m1r : m1r;
      const int m2c = jj ? -m2r : m2r;
      const int m3c = m1c + m2c;
      if (m3c < -L3 || m3c > L3) continue;
      const Cx u3 = Uc2r(m3r, m3c);
      if (u3.re == 0 && u3.im == 0) continue;
      const double cgv = cgd[(L1+m1c)*D2 + (L2+m2c)];
      if (cgv == 0) continue;
      const Cx u1 = Uc2r(m1r, m1c);
      const Cx u2 = Uc2r(m2r, m2c);
      const Cx p  = cmul(u1, u2);
      const Cx t  = cmul(p, Cx{u3.re, -u3.im});   // conj(U3)
      sre += t.re * cgv;
      sim += t.im * cgv;
    }
    tre[(a*D2+b)*D3+c] = sre;
    tim[(a*D2+b)*D3+c] = sim;
  }
  // tensor is purely real or purely imaginary; pick like the reference
  double mre = 0, mim = 0;
  for (int k = 0; k < D1*D2*D3; ++k){
    if (cfabs(tre[k]) > mre) mre = cfabs(tre[k]);
    if (cfabs(tim[k]) > mim) mim = cfabs(tim[k]);
  }
  CArr<L1,L2,L3> o{};
  for (int k = 0; k < D1*D2*D3; ++k)
    o.v[k] = (float)((mre >= mim) ? tre[k] : tim[k]);
  return o;
}

template<int L1,int L2,int L3>
constexpr CArr<L1,L2,L3> CG_V = buildCG<L1,L2,L3>();

constexpr int lminf(int a,int b){ return a > b ? a - b : b - a; }
constexpr int lmaxf(int a,int b){ return (a + b < 4) ? (a + b) : 4; }
constexpr int cplIndex(int l1,int l2,int lo){
  int idx = 0;
  for (int a = 0; a <= 3; ++a)
    for (int b = 0; b <= 3; ++b){
      const int c0 = lminf(a,b), c1 = lmaxf(a,b);
      for (int c = c0; c <= c1; ++c){
        if (a == l1 && b == l2 && c == lo) return idx;
        ++idx;
      }
    }
  return -1;
}
constexpr int poff(int l1,int l2,int lo){
  int s = 0;
  for (int c = lminf(l1,l2); c < lo; ++c) s += 2*c + 1;
  return s;
}
constexpr int psize(int l1,int l2){ return poff(l1, l2, lmaxf(l1,l2) + 1); }

// first pq index (in P-major execution order) whose cg for slot (LO,M) is
// nonzero -> that FMA becomes a plain mul (kills the part[] zero-init movs)
template<int L1,int L2,int LO>
constexpr int firstPQv(int M){
  const int NPQ = (2*L1+1)*(2*L2+1);
  for (int pq = 0; pq < NPQ; ++pq){
    const float v = CG_V<L1,L2,LO>.v[pq*(2*LO+1)+M];
    if (v > 1e-7f || v < -1e-7f) return pq;
  }
  return -1;
}

// EXECUTION ORDER of the 16 (l1,l2) groups: diagonal first (computed before
// the barrier, f-independent), then the off-diagonal remainder. acc[]
// first-touch logic MUST follow this order, not row-major!
constexpr int ORD_L1[16] = {0,1,2,3, 0,0,0, 1,1,1, 2,2,2, 3,3,3};
constexpr int ORD_L2[16] = {0,1,2,3, 1,2,3, 0,2,3, 0,1,3, 0,1,2};

// is (l1,l2) the FIRST group in execution order that couples into lo?
constexpr bool isAccFirstOrd(int l1,int l2,int lo){
  for (int k = 0; k < 16; ++k){
    const int a = ORD_L1[k], b = ORD_L2[k];
    if (lminf(a,b) <= lo && lo <= lmaxf(a,b))
      return (a == l1) && (b == l2);
  }
  return false;
}

} // namespace cgc

// ======================= device helpers =======================
__device__ __forceinline__ unsigned short f2bf(float x){
  unsigned u = __float_as_uint(x);
  u += 0x7fffu + ((u >> 16) & 1u);       // RNE
  return (unsigned short)(u >> 16);
}

// W pre-packed into bf16 MFMA B-fragment order: [i][ntile][kstep][lane][8]
__device__ __attribute__((aligned(16))) unsigned short WF[81920];

// per-thread radial-filter values: 40 bf16 packed in 20 dwords (5x ds_read_b128)
struct FU { unsigned u[20]; };

template<int I>
__device__ __forceinline__ float getF(const FU& f){
  const unsigned w = f.u[I >> 1];
  return __uint_as_float((I & 1) ? (w & 0xffff0000u) : (w << 16));
}

// ---- CG accumulation: ALL indices template params -> literal coefficients,
// zeros deleted, first touch per slot is a write (no zero-init). ----
template<int L1,int L2,int PQ,int LO,int LMAX,int M>
struct EmitM {
  static __device__ __forceinline__ void run(float t, float* __restrict__ part){
    constexpr float cg = cgc::CG_V<L1,L2,LO>.v[PQ*(2*LO+1) + M];
    if constexpr (cg > 1e-7f || cg < -1e-7f){
      constexpr int off = cgc::poff(L1,L2,LO) + M;
      if constexpr (PQ == cgc::firstPQv<L1,L2,LO>(M))
        part[off] = cg * t;
      else
        part[off] = fmaf(cg, t, part[off]);
    }
    if constexpr (M + 1 < 2*LO + 1)
      EmitM<L1,L2,PQ,LO,LMAX,M+1>::run(t, part);
    else if constexpr (LO < LMAX)
      EmitM<L1,L2,PQ,LO+1,LMAX,0>::run(t, part);
  }
};

template<int L1,int L2,int P,int Q>
struct PQLoop {
  static __device__ __forceinline__ void run(const float* __restrict__ xr,
                                             const float* __restrict__ yr,
                                             float* __restrict__ part){
    const float t = xr[L1*L1 + P] * yr[L2*L2 + Q];
    EmitM<L1, L2, P*(2*L2+1)+Q, cgc::lminf(L1,L2), cgc::lmaxf(L1,L2), 0>::run(t, part);
    if constexpr (Q + 1 < 2*L2 + 1)
      PQLoop<L1,L2,P,Q+1>::run(xr, yr, part);
    else if constexpr (P + 1 < 2*L1 + 1)
      PQLoop<L1,L2,P+1,0>::run(xr, yr, part);
  }
};

template<int L1,int L2,int LO,int M>
struct ScaleM {
  static __device__ __forceinline__ void run(const float* __restrict__ part,
                                             float* __restrict__ acc, float fv){
    constexpr int s = LO*LO + M;
    constexpr bool touched = (cgc::firstPQv<L1,L2,LO>(M) != -1);
    if constexpr (cgc::isAccFirstOrd(L1,L2,LO)){
      if constexpr (touched) acc[s] = fv * part[cgc::poff(L1,L2,LO) + M];
      else                   acc[s] = 0.f;
    } else if constexpr (touched){
      acc[s] = fmaf(fv, part[cgc::poff(L1,L2,LO) + M], acc[s]);
    }
    if constexpr (M + 1 < 2*LO + 1) ScaleM<L1,L2,LO,M+1>::run(part, acc, fv);
  }
};

template<int L1,int L2,int LO,int LMAX>
struct ScaleAccum {
  static __device__ __forceinline__ void run(const float* __restrict__ part,
                                             float* __restrict__ acc,
                                             const FU& fu){
    const float fv = getF<cgc::cplIndex(L1,L2,LO)>(fu);
    ScaleM<L1,L2,LO,0>::run(part, acc, fv);
    if constexpr (LO < LMAX) ScaleAccum<L1,L2,LO+1,LMAX>::run(part, acc, fu);
  }
};

template<int L1,int L2>
__device__ __forceinline__ void computePart(const float* __restrict__ xr,
                                            const float* __restrict__ yr,
                                            float* __restrict__ part){
  PQLoop<L1,L2,0,0>::run(xr, yr, part);
}

template<int L1,int L2>
__device__ __forceinline__ void scalePart(const float* __restrict__ part,
                                          float* __restrict__ acc,
                                          const FU& fu){
  ScaleAccum<L1,L2,cgc::lminf(L1,L2),cgc::lmaxf(L1,L2)>::run(part, acc, fu);
}

template<int L1,int L2>
__device__ __forceinline__ void doGroup(const float* __restrict__ xr,
                                        const float* __restrict__ yr,
                                        float* __restrict__ acc,
                                        const FU& fu){
  float part[cgc::psize(L1,L2)];
  computePart<L1,L2>(xr, yr, part);
  scalePart<L1,L2>(part, acc, fu);
}

// ======================= kernels =======================
__global__ __launch_bounds__(256) void prep_wf(const float* __restrict__ W){
  const int idx = blockIdx.x*256 + threadIdx.x;         // 81920 total
  const int j = idx & 7;
  const int l = (idx >> 3) & 63;
  const int s = (idx >> 9) & 1;
  const int t = (idx >> 10) & 1;
  const int i = idx >> 11;
  const int k   = s*32 + ((l >> 4) << 3) + j;           // contiguous-8 k per lane
  const int col = (t << 4) + (l & 15);
  WF[idx] = f2bf(W[(i << 11) + (k << 5) + col]);
}

// Fm layout: n-major per edge row: u16 index = el*1280 + n*40 + i.
// -> phase-2 thread (el,n) reads its 40 f-values as 80 contiguous, 16B-aligned
//    bytes = 5x ds_read_b128.
//
// RESTRUCTURE (round 7): ~90% of the CG contraction is f-independent. The
// 4 DIAGONAL groups (0,0),(1,1),(2,2),(3,3) -- which together consume every
// xr/yr component -- are computed into persistent part[] arrays BEFORE the
// barrier. So the x/y loads' uses sit pre-barrier in the same basic block:
// the machine scheduler hoists the loads to the top (MLP with phase-1's
// r/WF loads) and IR sinking CANNOT push them past the barrier (rounds 4-6
// failure mode). Waves reach the barrier after ~equal work -> minimal skew.
// After the barrier: read fu, scale the 4 held groups into acc, then the 12
// off-diagonal groups compute+scale one at a time (part <= 24 regs).
// acc first-touch follows the NEW execution order (isAccFirstOrd).
// __launch_bounds__(512, 4): VGPR cap 128; peak live ~= 32 x/y + 60 parts
// + 20 fu + temps ~= 120.
__global__ __launch_bounds__(512, 4) void pairmix(const float* __restrict__ x,
                                                  const float* __restrict__ y,
                                                  const float* __restrict__ r,
                                                  float* __restrict__ out){
  __shared__ unsigned short Fm[16*1280];                // 40960 B
  const int e0   = blockIdx.x << 4;                     // 16 edges per block
  const int tid  = threadIdx.x;
  const int lane = tid & 63;
  const int wv   = tid >> 6;                            // 0..7

  // ---- x/y loads: issued first (oldest in vmcnt queue; phase-1's waits
  //      drain them for free while phase-1 stalls on its own loads) ----
  const int n  = tid & 31;
  const int el = tid >> 5;                              // 0..15
  const float* xp = x + (size_t)(e0 + el)*512 + n;
  const float* yp = y + (size_t)(e0 + el)*512 + n;
  float xr_[16], yr_[16];
  #pragma unroll
  for (int s = 0; s < 16; ++s){ xr_[s] = xp[s << 5]; yr_[s] = yp[s << 5]; }

  // ---- Phase 1: F = r @ W via bf16 MFMA (M=16 edges, N=1280, K=64) ----
  {
    const int mrow = lane & 15;                         // edge row
    const int kch  = (lane >> 4) << 3;                  // k chunk base
    const float* rp = r + (size_t)(e0 + mrow)*64 + kch;
    s8_t A[2];
    #pragma unroll
    for (int s = 0; s < 2; ++s){
      const float4 v0 = *(const float4*)(rp + s*32);
      const float4 v1 = *(const float4*)(rp + s*32 + 4);
      union { s8_t v; unsigned u[4]; } pk;
      pk.u[0] = (unsigned)f2bf(v0.x) | ((unsigned)f2bf(v0.y) << 16);
      pk.u[1] = (unsigned)f2bf(v0.z) | ((unsigned)f2bf(v0.w) << 16);
      pk.u[2] = (unsigned)f2bf(v1.x) | ((unsigned)f2bf(v1.y) << 16);
      pk.u[3] = (unsigned)f2bf(v1.z) | ((unsigned)f2bf(v1.w) << 16);
      A[s] = pk.v;
    }
    #pragma unroll
    for (int tt = 0; tt < 10; ++tt){                    // 8 waves x 10 = 80 tiles
      const int T  = wv*10 + tt;
      const int ci = T >> 1;                            // coupling 0..39
      const int th = T & 1;                             // n-half 0..1
      const s8_t B0 = *(const s8_t*)(WF + ((((ci*2 + th)*2 + 0)*64 + lane) << 3));
      const s8_t B1 = *(const s8_t*)(WF + ((((ci*2 + th)*2 + 1)*64 + lane) << 3));
      f4_t c = {0.f, 0.f, 0.f, 0.f};
      c = __builtin_amdgcn_mfma_f32_16x16x32_bf16(A[0], B0, c, 0, 0, 0);
      c = __builtin_amdgcn_mfma_f32_16x16x32_bf16(A[1], B1, c, 0, 0, 0);
      const int colN = th*16 + (lane & 15);             // channel n
      const int rb   = (lane >> 4) << 2;                // row-group base (edge)
      #pragma unroll
      for (int jj = 0; jj < 4; ++jj)
        Fm[(rb + jj)*1280 + colN*40 + ci] = f2bf(c[jj]); // C/D: col=lane&15, row=(lane>>4)*4+reg
    }
  }

  // ---- Pre-barrier: f-independent CG parts for the 4 diagonal groups ----
  float p00[cgc::psize(0,0)];   // 1
  float p11[cgc::psize(1,1)];   // 9
  float p22[cgc::psize(2,2)];   // 25
  float p33[cgc::psize(3,3)];   // 25
  computePart<0,0>(xr_, yr_, p00);
  computePart<1,1>(xr_, yr_, p11);
  computePart<2,2>(xr_, yr_, p22);
  computePart<3,3>(xr_, yr_, p33);

  __syncthreads();

  // ---- Post-barrier: radial filters + scaling + off-diagonal groups ----
  FU fu;
  const unsigned short* fB = &Fm[el*1280 + n*40];
  #pragma unroll
  for (int j = 0; j < 5; ++j)
    ((s8_t*)fu.u)[j] = *(const s8_t*)(fB + j*8);

  float acc[25];                                        // first-touch-written per isAccFirstOrd

  scalePart<0,0>(p00, acc, fu);
  scalePart<1,1>(p11, acc, fu);
  scalePart<2,2>(p22, acc, fu);
  scalePart<3,3>(p33, acc, fu);

  doGroup<0,1>(xr_, yr_, acc, fu);
  doGroup<0,2>(xr_, yr_, acc, fu);
  doGroup<0,3>(xr_, yr_, acc, fu);
  doGroup<1,0>(xr_, yr_, acc, fu);
  doGroup<1,2>(xr_, yr_, acc, fu);
  doGroup<1,3>(xr_, yr_, acc, fu);
  doGroup<2,0>(xr_, yr_, acc, fu);
  doGroup<2,1>(xr_, yr_, acc, fu);
  doGroup<2,3>(xr_, yr_, acc, fu);
  doGroup<3,0>(xr_, yr_, acc, fu);
  doGroup<3,1>(xr_, yr_, acc, fu);
  doGroup<3,2>(xr_, yr_, acc, fu);

  float* op = out + (size_t)(e0 + el)*800 + n;
  #pragma unroll
  for (int s = 0; s < 25; ++s) op[s << 5] = acc[s];
}

// ======================= launch =======================
extern "C" void kernel_launch(void* const* d_in, const int* in_sizes, int n_in,
                              void* d_out, int out_size, void* d_ws, size_t ws_size,
                              hipStream_t stream){
  const float* x = (const float*)d_in[0];
  const float* y = (const float*)d_in[1];
  const float* r = (const float*)d_in[2];
  const float* W = (const float*)d_in[3];
  float* out = (float*)d_out;

  const int E = in_sizes[0] / 512;                      // 100000

  prep_wf<<<320, 256, 0, stream>>>(W);                  // 81920 threads
  pairmix<<<E / 16, 512, 0, stream>>>(x, y, r, out);
}

// Round 8
// 219.764 us; speedup vs baseline: 1.5687x; 1.0715x over previous
//
#include <hip/hip_runtime.h>

typedef short s8_t __attribute__((ext_vector_type(8)));
typedef float f4_t __attribute__((ext_vector_type(4)));

// ======================= compile-time Clebsch-Gordan =======================
namespace cgc {

struct Cx { double re, im; };

constexpr double FACT[13] = {1.,1.,2.,6.,24.,120.,720.,5040.,40320.,362880.,
                             3628800.,39916800.,479001600.};

constexpr double cfabs(double x){ return x < 0 ? -x : x; }

constexpr double csqrt(double x){
  if (x <= 0) return 0;
  double g = x > 1 ? x : 1.0;
  for (int i = 0; i < 80; ++i){
    double ng = 0.5*(g + x/g);
    if (ng == g) break;
    g = ng;
  }
  return g;
}

constexpr int imax3(int a,int b,int c){ int m=a; if(b>m)m=b; if(c>m)m=c; return m; }
constexpr int imin3(int a,int b,int c){ int m=a; if(b<m)m=b; if(c<m)m=c; return m; }

constexpr double clebsch(int j1,int m1,int j2,int m2,int j3,int m3){
  if (m1 + m2 != m3) return 0;
  const int jmin = j1 > j2 ? j1 - j2 : j2 - j1;
  if (j3 < jmin || j3 > j1 + j2) return 0;
  if (m1 < -j1 || m1 > j1 || m2 < -j2 || m2 > j2 || m3 < -j3 || m3 > j3) return 0;
  double pref = csqrt((2*j3+1)*FACT[j3+j1-j2]*FACT[j3-j1+j2]*FACT[j1+j2-j3]/FACT[j1+j2+j3+1]);
  pref *= csqrt(FACT[j3+m3]*FACT[j3-m3]*FACT[j1-m1]*FACT[j1+m1]*FACT[j2-m2]*FACT[j2+m2]);
  const int kmin = imax3(0, j2-j3-m1, j1-j3+m2);
  const int kmax = imin3(j1+j2-j3, j1-m1, j2+m2);
  double s = 0;
  for (int k = kmin; k <= kmax; ++k){
    double d = FACT[k]*FACT[j1+j2-j3-k]*FACT[j1-m1-k]*FACT[j2+m2-k]
             * FACT[j3-j2+m1+k]*FACT[j3-j1-m2+k];
    s += ((k & 1) ? -1.0 : 1.0) / d;
  }
  return pref * s;
}

constexpr Cx cmul(Cx a, Cx b){ return Cx{a.re*b.re - a.im*b.im, a.re*b.im + a.im*b.re}; }

// U[l+mr][l+mc] of the complex->real SH transform (row: real m, col: complex m)
constexpr Cx Uc2r(int mr, int mc){
  const double s2i = 0.70710678118654752440;
  if (mr == 0) return (mc == 0) ? Cx{1.,0.} : Cx{0.,0.};
  if (mr > 0){
    if (mc ==  mr) return Cx{ (mr & 1) ? -s2i : s2i, 0. };
    if (mc == -mr) return Cx{ s2i, 0. };
    return Cx{0.,0.};
  }
  const int m = -mr;
  if (mc ==  m) return Cx{0., (m & 1) ?  s2i : -s2i };
  if (mc == -m) return Cx{0., s2i };
  return Cx{0.,0.};
}

template<int L1,int L2,int L3>
struct CArr { float v[(2*L1+1)*(2*L2+1)*(2*L3+1)]; };

template<int L1,int L2,int L3>
constexpr CArr<L1,L2,L3> buildCG(){
  constexpr int D1 = 2*L1+1, D2 = 2*L2+1, D3 = 2*L3+1;
  // complex-basis CG cached once per coupling (m3 = m1+m2 enforced)
  double cgd[D1*D2] = {};
  for (int i = 0; i < D1; ++i)
    for (int j = 0; j < D2; ++j){
      const int m1c = i - L1, m2c = j - L2, m3c = m1c + m2c;
      cgd[i*D2+j] = (m3c < -L3 || m3c > L3) ? 0.0 : clebsch(L1,m1c,L2,m2c,L3,m3c);
    }
  double tre[D1*D2*D3] = {};
  double tim[D1*D2*D3] = {};
  for (int a = 0; a < D1; ++a)
  for (int b = 0; b < D2; ++b)
  for (int c = 0; c < D3; ++c){
    const int m1r = a - L1, m2r = b - L2, m3r = c - L3;
    double sre = 0, sim = 0;
    const int n1 = (m1r == 0) ? 1 : 2;
    const int n2 = (m2r == 0) ? 1 : 2;
    for (int ii = 0; ii < n1; ++ii)
    for (int jj = 0; jj < n2; ++jj){
      const int m1c = ii ? -m1r : m1r;
      const int m2c = jj ? -m2r : m2r;
      const int m3c = m1c + m2c;
      if (m3c < -L3 || m3c > L3) continue;
      const Cx u3 = Uc2r(m3r, m3c);
      if (u3.re == 0 && u3.im == 0) continue;
      const double cgv = cgd[(L1+m1c)*D2 + (L2+m2c)];
      if (cgv == 0) continue;
      const Cx u1 = Uc2r(m1r, m1c);
      const Cx u2 = Uc2r(m2r, m2c);
      const Cx p  = cmul(u1, u2);
      const Cx t  = cmul(p, Cx{u3.re, -u3.im});   // conj(U3)
      sre += t.re * cgv;
      sim += t.im * cgv;
    }
    tre[(a*D2+b)*D3+c] = sre;
    tim[(a*D2+b)*D3+c] = sim;
  }
  // tensor is purely real or purely imaginary; pick like the reference
  double mre = 0, mim = 0;
  for (int k = 0; k < D1*D2*D3; ++k){
    if (cfabs(tre[k]) > mre) mre = cfabs(tre[k]);
    if (cfabs(tim[k]) > mim) mim = cfabs(tim[k]);
  }
  CArr<L1,L2,L3> o{};
  for (int k = 0; k < D1*D2*D3; ++k)
    o.v[k] = (float)((mre >= mim) ? tre[k] : tim[k]);
  return o;
}

template<int L1,int L2,int L3>
constexpr CArr<L1,L2,L3> CG_V = buildCG<L1,L2,L3>();

constexpr int lminf(int a,int b){ return a > b ? a - b : b - a; }
constexpr int lmaxf(int a,int b){ return (a + b < 4) ? (a + b) : 4; }
constexpr int cplIndex(int l1,int l2,int lo){
  int idx = 0;
  for (int a = 0; a <= 3; ++a)
    for (int b = 0; b <= 3; ++b){
      const int c0 = lminf(a,b), c1 = lmaxf(a,b);
      for (int c = c0; c <= c1; ++c){
        if (a == l1 && b == l2 && c == lo) return idx;
        ++idx;
      }
    }
  return -1;
}
constexpr int poff(int l1,int l2,int lo){
  int s = 0;
  for (int c = lminf(l1,l2); c < lo; ++c) s += 2*c + 1;
  return s;
}
constexpr int psize(int l1,int l2){ return poff(l1, l2, lmaxf(l1,l2) + 1); }

// first pq index (in P-major execution order) whose cg for slot (LO,M) is
// nonzero -> that FMA becomes a plain mul (kills the part[] zero-init movs)
template<int L1,int L2,int LO>
constexpr int firstPQv(int M){
  const int NPQ = (2*L1+1)*(2*L2+1);
  for (int pq = 0; pq < NPQ; ++pq){
    const float v = CG_V<L1,L2,LO>.v[pq*(2*LO+1)+M];
    if (v > 1e-7f || v < -1e-7f) return pq;
  }
  return -1;
}

// EXECUTION ORDER of the 16 (l1,l2) groups: diagonal first (computed before
// the barrier, f-independent), then the off-diagonal remainder. acc[]
// first-touch logic MUST follow this order, not row-major!
constexpr int ORD_L1[16] = {0,1,2,3, 0,0,0, 1,1,1, 2,2,2, 3,3,3};
constexpr int ORD_L2[16] = {0,1,2,3, 1,2,3, 0,2,3, 0,1,3, 0,1,2};

// is (l1,l2) the FIRST group in execution order that couples into lo?
constexpr bool isAccFirstOrd(int l1,int l2,int lo){
  for (int k = 0; k < 16; ++k){
    const int a = ORD_L1[k], b = ORD_L2[k];
    if (lminf(a,b) <= lo && lo <= lmaxf(a,b))
      return (a == l1) && (b == l2);
  }
  return false;
}

} // namespace cgc

// ======================= device helpers =======================
__device__ __forceinline__ unsigned short f2bf(float x){
  unsigned u = __float_as_uint(x);
  u += 0x7fffu + ((u >> 16) & 1u);       // RNE
  return (unsigned short)(u >> 16);
}

// W pre-packed into bf16 MFMA B-fragment order: [i][ntile][kstep][lane][8]
__device__ __attribute__((aligned(16))) unsigned short WF[81920];

// per-thread radial-filter values: 40 bf16 packed in 20 dwords (5x ds_read_b128)
struct FU { unsigned u[20]; };

template<int I>
__device__ __forceinline__ float getF(const FU& f){
  const unsigned w = f.u[I >> 1];
  return __uint_as_float((I & 1) ? (w & 0xffff0000u) : (w << 16));
}

// ---- CG accumulation: ALL indices template params -> literal coefficients,
// zeros deleted, first touch per slot is a write (no zero-init). ----
template<int L1,int L2,int PQ,int LO,int LMAX,int M>
struct EmitM {
  static __device__ __forceinline__ void run(float t, float* __restrict__ part){
    constexpr float cg = cgc::CG_V<L1,L2,LO>.v[PQ*(2*LO+1) + M];
    if constexpr (cg > 1e-7f || cg < -1e-7f){
      constexpr int off = cgc::poff(L1,L2,LO) + M;
      if constexpr (PQ == cgc::firstPQv<L1,L2,LO>(M))
        part[off] = cg * t;
      else
        part[off] = fmaf(cg, t, part[off]);
    }
    if constexpr (M + 1 < 2*LO + 1)
      EmitM<L1,L2,PQ,LO,LMAX,M+1>::run(t, part);
    else if constexpr (LO < LMAX)
      EmitM<L1,L2,PQ,LO+1,LMAX,0>::run(t, part);
  }
};

template<int L1,int L2,int P,int Q>
struct PQLoop {
  static __device__ __forceinline__ void run(const float* __restrict__ xr,
                                             const float* __restrict__ yr,
                                             float* __restrict__ part){
    const float t = xr[L1*L1 + P] * yr[L2*L2 + Q];
    EmitM<L1, L2, P*(2*L2+1)+Q, cgc::lminf(L1,L2), cgc::lmaxf(L1,L2), 0>::run(t, part);
    if constexpr (Q + 1 < 2*L2 + 1)
      PQLoop<L1,L2,P,Q+1>::run(xr, yr, part);
    else if constexpr (P + 1 < 2*L1 + 1)
      PQLoop<L1,L2,P+1,0>::run(xr, yr, part);
  }
};

template<int L1,int L2,int LO,int M>
struct ScaleM {
  static __device__ __forceinline__ void run(const float* __restrict__ part,
                                             float* __restrict__ acc, float fv){
    constexpr int s = LO*LO + M;
    constexpr bool touched = (cgc::firstPQv<L1,L2,LO>(M) != -1);
    if constexpr (cgc::isAccFirstOrd(L1,L2,LO)){
      if constexpr (touched) acc[s] = fv * part[cgc::poff(L1,L2,LO) + M];
      else                   acc[s] = 0.f;
    } else if constexpr (touched){
      acc[s] = fmaf(fv, part[cgc::poff(L1,L2,LO) + M], acc[s]);
    }
    if constexpr (M + 1 < 2*LO + 1) ScaleM<L1,L2,LO,M+1>::run(part, acc, fv);
  }
};

template<int L1,int L2,int LO,int LMAX>
struct ScaleAccum {
  static __device__ __forceinline__ void run(const float* __restrict__ part,
                                             float* __restrict__ acc,
                                             const FU& fu){
    const float fv = getF<cgc::cplIndex(L1,L2,LO)>(fu);
    ScaleM<L1,L2,LO,0>::run(part, acc, fv);
    if constexpr (LO < LMAX) ScaleAccum<L1,L2,LO+1,LMAX>::run(part, acc, fu);
  }
};

template<int L1,int L2>
__device__ __forceinline__ void computePart(const float* __restrict__ xr,
                                            const float* __restrict__ yr,
                                            float* __restrict__ part){
  PQLoop<L1,L2,0,0>::run(xr, yr, part);
}

template<int L1,int L2>
__device__ __forceinline__ void scalePart(const float* __restrict__ part,
                                          float* __restrict__ acc,
                                          const FU& fu){
  ScaleAccum<L1,L2,cgc::lminf(L1,L2),cgc::lmaxf(L1,L2)>::run(part, acc, fu);
}

template<int L1,int L2>
__device__ __forceinline__ void doGroup(const float* __restrict__ xr,
                                        const float* __restrict__ yr,
                                        float* __restrict__ acc,
                                        const FU& fu){
  float part[cgc::psize(L1,L2)];
  computePart<L1,L2>(xr, yr, part);
  scalePart<L1,L2>(part, acc, fu);
}

// ======================= kernels =======================
__global__ __launch_bounds__(256) void prep_wf(const float* __restrict__ W){
  const int idx = blockIdx.x*256 + threadIdx.x;         // 81920 total
  const int j = idx & 7;
  const int l = (idx >> 3) & 63;
  const int s = (idx >> 9) & 1;
  const int t = (idx >> 10) & 1;
  const int i = idx >> 11;
  const int k   = s*32 + ((l >> 4) << 3) + j;           // contiguous-8 k per lane
  const int col = (t << 4) + (l & 15);
  WF[idx] = f2bf(W[(i << 11) + (k << 5) + col]);
}

// Fm layout: n-major per edge row: u16 index = el*1280 + n*40 + i.
// -> phase-2 thread (el,n) reads its 40 f-values as 80 contiguous, 16B-aligned
//    bytes = 5x ds_read_b128.
//
// Structure (round 7): diagonal groups' f-independent CG parts computed
// BEFORE the barrier (x/y loads get pre-barrier uses -> hoisted, MLP with
// phase-1 loads); off-diagonal groups after.
//
// ROUND 8 FIX: round 7 spilled (VGPR=64, +308 MB scratch traffic) because
// __launch_bounds__'s 2nd arg only sets a MINIMUM waves/EU -- the backend
// targeted the LDS-allowed occupancy (40960 B -> 4 blocks/CU -> 8 waves/EU)
// and pinned the VGPR budget at 512/8=64, spilling the pre-barrier parts.
// amdgpu_waves_per_eu(4,4) pins min=max=4 waves/EU -> VGPR budget 128.
// Peak live ~= 32 x/y + 60 parts + 20 fu + temps ~= 120 < 128 -> no spill.
__global__ __launch_bounds__(512)
__attribute__((amdgpu_waves_per_eu(4,4)))
void pairmix(const float* __restrict__ x,
             const float* __restrict__ y,
             const float* __restrict__ r,
             float* __restrict__ out){
  __shared__ unsigned short Fm[16*1280];                // 40960 B
  const int e0   = blockIdx.x << 4;                     // 16 edges per block
  const int tid  = threadIdx.x;
  const int lane = tid & 63;
  const int wv   = tid >> 6;                            // 0..7

  // ---- x/y loads: issued first (oldest in vmcnt queue; phase-1's waits
  //      drain them for free while phase-1 stalls on its own loads) ----
  const int n  = tid & 31;
  const int el = tid >> 5;                              // 0..15
  const float* xp = x + (size_t)(e0 + el)*512 + n;
  const float* yp = y + (size_t)(e0 + el)*512 + n;
  float xr_[16], yr_[16];
  #pragma unroll
  for (int s = 0; s < 16; ++s){ xr_[s] = xp[s << 5]; yr_[s] = yp[s << 5]; }

  // ---- Phase 1: F = r @ W via bf16 MFMA (M=16 edges, N=1280, K=64) ----
  {
    const int mrow = lane & 15;                         // edge row
    const int kch  = (lane >> 4) << 3;                  // k chunk base
    const float* rp = r + (size_t)(e0 + mrow)*64 + kch;
    s8_t A[2];
    #pragma unroll
    for (int s = 0; s < 2; ++s){
      const float4 v0 = *(const float4*)(rp + s*32);
      const float4 v1 = *(const float4*)(rp + s*32 + 4);
      union { s8_t v; unsigned u[4]; } pk;
      pk.u[0] = (unsigned)f2bf(v0.x) | ((unsigned)f2bf(v0.y) << 16);
      pk.u[1] = (unsigned)f2bf(v0.z) | ((unsigned)f2bf(v0.w) << 16);
      pk.u[2] = (unsigned)f2bf(v1.x) | ((unsigned)f2bf(v1.y) << 16);
      pk.u[3] = (unsigned)f2bf(v1.z) | ((unsigned)f2bf(v1.w) << 16);
      A[s] = pk.v;
    }
    #pragma unroll
    for (int tt = 0; tt < 10; ++tt){                    // 8 waves x 10 = 80 tiles
      const int T  = wv*10 + tt;
      const int ci = T >> 1;                            // coupling 0..39
      const int th = T & 1;                             // n-half 0..1
      const s8_t B0 = *(const s8_t*)(WF + ((((ci*2 + th)*2 + 0)*64 + lane) << 3));
      const s8_t B1 = *(const s8_t*)(WF + ((((ci*2 + th)*2 + 1)*64 + lane) << 3));
      f4_t c = {0.f, 0.f, 0.f, 0.f};
      c = __builtin_amdgcn_mfma_f32_16x16x32_bf16(A[0], B0, c, 0, 0, 0);
      c = __builtin_amdgcn_mfma_f32_16x16x32_bf16(A[1], B1, c, 0, 0, 0);
      const int colN = th*16 + (lane & 15);             // channel n
      const int rb   = (lane >> 4) << 2;                // row-group base (edge)
      #pragma unroll
      for (int jj = 0; jj < 4; ++jj)
        Fm[(rb + jj)*1280 + colN*40 + ci] = f2bf(c[jj]); // C/D: col=lane&15, row=(lane>>4)*4+reg
    }
  }

  // ---- Pre-barrier: f-independent CG parts for the 4 diagonal groups ----
  float p00[cgc::psize(0,0)];   // 1
  float p11[cgc::psize(1,1)];   // 9
  float p22[cgc::psize(2,2)];   // 25
  float p33[cgc::psize(3,3)];   // 25
  computePart<0,0>(xr_, yr_, p00);
  computePart<1,1>(xr_, yr_, p11);
  computePart<2,2>(xr_, yr_, p22);
  computePart<3,3>(xr_, yr_, p33);

  __syncthreads();

  // ---- Post-barrier: radial filters + scaling + off-diagonal groups ----
  FU fu;
  const unsigned short* fB = &Fm[el*1280 + n*40];
  #pragma unroll
  for (int j = 0; j < 5; ++j)
    ((s8_t*)fu.u)[j] = *(const s8_t*)(fB + j*8);

  float acc[25];                                        // first-touch-written per isAccFirstOrd

  scalePart<0,0>(p00, acc, fu);
  scalePart<1,1>(p11, acc, fu);
  scalePart<2,2>(p22, acc, fu);
  scalePart<3,3>(p33, acc, fu);

  doGroup<0,1>(xr_, yr_, acc, fu);
  doGroup<0,2>(xr_, yr_, acc, fu);
  doGroup<0,3>(xr_, yr_, acc, fu);
  doGroup<1,0>(xr_, yr_, acc, fu);
  doGroup<1,2>(xr_, yr_, acc, fu);
  doGroup<1,3>(xr_, yr_, acc, fu);
  doGroup<2,0>(xr_, yr_, acc, fu);
  doGroup<2,1>(xr_, yr_, acc, fu);
  doGroup<2,3>(xr_, yr_, acc, fu);
  doGroup<3,0>(xr_, yr_, acc, fu);
  doGroup<3,1>(xr_, yr_, acc, fu);
  doGroup<3,2>(xr_, yr_, acc, fu);

  float* op = out + (size_t)(e0 + el)*800 + n;
  #pragma unroll
  for (int s = 0; s < 25; ++s) op[s << 5] = acc[s];
}

// ======================= launch =======================
extern "C" void kernel_launch(void* const* d_in, const int* in_sizes, int n_in,
                              void* d_out, int out_size, void* d_ws, size_t ws_size,
                              hipStream_t stream){
  const float* x = (const float*)d_in[0];
  const float* y = (const float*)d_in[1];
  const float* r = (const float*)d_in[2];
  const float* W = (const float*)d_in[3];
  float* out = (float*)d_out;

  const int E = in_sizes[0] / 512;                      // 100000

  prep_wf<<<320, 256, 0, stream>>>(W);                  // 81920 threads
  pairmix<<<E / 16, 512, 0, stream>>>(x, y, r, out);
}

// Round 9
// 193.511 us; speedup vs baseline: 1.7815x; 1.1357x over previous
//
#include <hip/hip_runtime.h>

typedef short s8_t __attribute__((ext_vector_type(8)));
typedef float f4_t __attribute__((ext_vector_type(4)));

// ======================= compile-time Clebsch-Gordan =======================
namespace cgc {

struct Cx { double re, im; };

constexpr double FACT[13] = {1.,1.,2.,6.,24.,120.,720.,5040.,40320.,362880.,
                             3628800.,39916800.,479001600.};

constexpr double cfabs(double x){ return x < 0 ? -x : x; }

constexpr double csqrt(double x){
  if (x <= 0) return 0;
  double g = x > 1 ? x : 1.0;
  for (int i = 0; i < 80; ++i){
    double ng = 0.5*(g + x/g);
    if (ng == g) break;
    g = ng;
  }
  return g;
}

constexpr int imax3(int a,int b,int c){ int m=a; if(b>m)m=b; if(c>m)m=c; return m; }
constexpr int imin3(int a,int b,int c){ int m=a; if(b<m)m=b; if(c<m)m=c; return m; }

constexpr double clebsch(int j1,int m1,int j2,int m2,int j3,int m3){
  if (m1 + m2 != m3) return 0;
  const int jmin = j1 > j2 ? j1 - j2 : j2 - j1;
  if (j3 < jmin || j3 > j1 + j2) return 0;
  if (m1 < -j1 || m1 > j1 || m2 < -j2 || m2 > j2 || m3 < -j3 || m3 > j3) return 0;
  double pref = csqrt((2*j3+1)*FACT[j3+j1-j2]*FACT[j3-j1+j2]*FACT[j1+j2-j3]/FACT[j1+j2+j3+1]);
  pref *= csqrt(FACT[j3+m3]*FACT[j3-m3]*FACT[j1-m1]*FACT[j1+m1]*FACT[j2-m2]*FACT[j2+m2]);
  const int kmin = imax3(0, j2-j3-m1, j1-j3+m2);
  const int kmax = imin3(j1+j2-j3, j1-m1, j2+m2);
  double s = 0;
  for (int k = kmin; k <= kmax; ++k){
    double d = FACT[k]*FACT[j1+j2-j3-k]*FACT[j1-m1-k]*FACT[j2+m2-k]
             * FACT[j3-j2+m1+k]*FACT[j3-j1-m2+k];
    s += ((k & 1) ? -1.0 : 1.0) / d;
  }
  return pref * s;
}

constexpr Cx cmul(Cx a, Cx b){ return Cx{a.re*b.re - a.im*b.im, a.re*b.im + a.im*b.re}; }

// U[l+mr][l+mc] of the complex->real SH transform (row: real m, col: complex m)
constexpr Cx Uc2r(int mr, int mc){
  const double s2i = 0.70710678118654752440;
  if (mr == 0) return (mc == 0) ? Cx{1.,0.} : Cx{0.,0.};
  if (mr > 0){
    if (mc ==  mr) return Cx{ (mr & 1) ? -s2i : s2i, 0. };
    if (mc == -mr) return Cx{ s2i, 0. };
    return Cx{0.,0.};
  }
  const int m = -mr;
  if (mc ==  m) return Cx{0., (m & 1) ?  s2i : -s2i };
  if (mc == -m) return Cx{0., s2i };
  return Cx{0.,0.};
}

template<int L1,int L2,int L3>
struct CArr { float v[(2*L1+1)*(2*L2+1)*(2*L3+1)]; };

template<int L1,int L2,int L3>
constexpr CArr<L1,L2,L3> buildCG(){
  constexpr int D1 = 2*L1+1, D2 = 2*L2+1, D3 = 2*L3+1;
  // complex-basis CG cached once per coupling (m3 = m1+m2 enforced)
  double cgd[D1*D2] = {};
  for (int i = 0; i < D1; ++i)
    for (int j = 0; j < D2; ++j){
      const int m1c = i - L1, m2c = j - L2, m3c = m1c + m2c;
      cgd[i*D2+j] = (m3c < -L3 || m3c > L3) ? 0.0 : clebsch(L1,m1c,L2,m2c,L3,m3c);
    }
  double tre[D1*D2*D3] = {};
  double tim[D1*D2*D3] = {};
  for (int a = 0; a < D1; ++a)
  for (int b = 0; b < D2; ++b)
  for (int c = 0; c < D3; ++c){
    const int m1r = a - L1, m2r = b - L2, m3r = c - L3;
    double sre = 0, sim = 0;
    const int n1 = (m1r == 0) ? 1 : 2;
    const int n2 = (m2r == 0) ? 1 : 2;
    for (int ii = 0; ii < n1; ++ii)
    for (int jj = 0; jj < n2; ++jj){
      const int m1c = ii ? -m1r : m1r;
      const int m2c = jj ? -m2r : m2r;
      const int m3c = m1c + m2c;
      if (m3c < -L3 || m3c > L3) continue;
      const Cx u3 = Uc2r(m3r, m3c);
      if (u3.re == 0 && u3.im == 0) continue;
      const double cgv = cgd[(L1+m1c)*D2 + (L2+m2c)];
      if (cgv == 0) continue;
      const Cx u1 = Uc2r(m1r, m1c);
      const Cx u2 = Uc2r(m2r, m2c);
      const Cx p  = cmul(u1, u2);
      const Cx t  = cmul(p, Cx{u3.re, -u3.im});   // conj(U3)
      sre += t.re * cgv;
      sim += t.im * cgv;
    }
    tre[(a*D2+b)*D3+c] = sre;
    tim[(a*D2+b)*D3+c] = sim;
  }
  // tensor is purely real or purely imaginary; pick like the reference
  double mre = 0, mim = 0;
  for (int k = 0; k < D1*D2*D3; ++k){
    if (cfabs(tre[k]) > mre) mre = cfabs(tre[k]);
    if (cfabs(tim[k]) > mim) mim = cfabs(tim[k]);
  }
  CArr<L1,L2,L3> o{};
  for (int k = 0; k < D1*D2*D3; ++k)
    o.v[k] = (float)((mre >= mim) ? tre[k] : tim[k]);
  return o;
}

template<int L1,int L2,int L3>
constexpr CArr<L1,L2,L3> CG_V = buildCG<L1,L2,L3>();

constexpr int lminf(int a,int b){ return a > b ? a - b : b - a; }
constexpr int lmaxf(int a,int b){ return (a + b < 4) ? (a + b) : 4; }
constexpr int cplIndex(int l1,int l2,int lo){
  int idx = 0;
  for (int a = 0; a <= 3; ++a)
    for (int b = 0; b <= 3; ++b){
      const int c0 = lminf(a,b), c1 = lmaxf(a,b);
      for (int c = c0; c <= c1; ++c){
        if (a == l1 && b == l2 && c == lo) return idx;
        ++idx;
      }
    }
  return -1;
}
constexpr int poff(int l1,int l2,int lo){
  int s = 0;
  for (int c = lminf(l1,l2); c < lo; ++c) s += 2*c + 1;
  return s;
}
constexpr int psize(int l1,int l2){ return poff(l1, l2, lmaxf(l1,l2) + 1); }

// first pq index (in P-major execution order) whose cg for slot (LO,M) is
// nonzero -> that FMA becomes a plain mul (kills the part[] zero-init movs)
template<int L1,int L2,int LO>
constexpr int firstPQv(int M){
  const int NPQ = (2*L1+1)*(2*L2+1);
  for (int pq = 0; pq < NPQ; ++pq){
    const float v = CG_V<L1,L2,LO>.v[pq*(2*LO+1)+M];
    if (v > 1e-7f || v < -1e-7f) return pq;
  }
  return -1;
}

// EXECUTION ORDER of the 16 (l1,l2) groups: diagonal first (computed before
// the barrier, f-independent), then the off-diagonal remainder. acc[]
// first-touch logic MUST follow this order, not row-major!
constexpr int ORD_L1[16] = {0,1,2,3, 0,0,0, 1,1,1, 2,2,2, 3,3,3};
constexpr int ORD_L2[16] = {0,1,2,3, 1,2,3, 0,2,3, 0,1,3, 0,1,2};

// is (l1,l2) the FIRST group in execution order that couples into lo?
constexpr bool isAccFirstOrd(int l1,int l2,int lo){
  for (int k = 0; k < 16; ++k){
    const int a = ORD_L1[k], b = ORD_L2[k];
    if (lminf(a,b) <= lo && lo <= lmaxf(a,b))
      return (a == l1) && (b == l2);
  }
  return false;
}

} // namespace cgc

// ======================= device helpers =======================
__device__ __forceinline__ unsigned short f2bf(float x){
  unsigned u = __float_as_uint(x);
  u += 0x7fffu + ((u >> 16) & 1u);       // RNE
  return (unsigned short)(u >> 16);
}
__device__ __forceinline__ float bf2f(unsigned short h){
  return __uint_as_float(((unsigned)h) << 16);
}

// W pre-packed into bf16 MFMA B-fragment order: [i][ntile][kstep][lane][8]
__device__ __attribute__((aligned(16))) unsigned short WF[81920];

// ---- CG accumulation: ALL indices template params -> literal coefficients,
// zeros deleted, first touch per slot is a write (no zero-init). ----
template<int L1,int L2,int PQ,int LO,int LMAX,int M>
struct EmitM {
  static __device__ __forceinline__ void run(float t, float* __restrict__ part){
    constexpr float cg = cgc::CG_V<L1,L2,LO>.v[PQ*(2*LO+1) + M];
    if constexpr (cg > 1e-7f || cg < -1e-7f){
      constexpr int off = cgc::poff(L1,L2,LO) + M;
      if constexpr (PQ == cgc::firstPQv<L1,L2,LO>(M))
        part[off] = cg * t;
      else
        part[off] = fmaf(cg, t, part[off]);
    }
    if constexpr (M + 1 < 2*LO + 1)
      EmitM<L1,L2,PQ,LO,LMAX,M+1>::run(t, part);
    else if constexpr (LO < LMAX)
      EmitM<L1,L2,PQ,LO+1,LMAX,0>::run(t, part);
  }
};

template<int L1,int L2,int P,int Q>
struct PQLoop {
  static __device__ __forceinline__ void run(const float* __restrict__ xr,
                                             const float* __restrict__ yr,
                                             float* __restrict__ part){
    const float t = xr[L1*L1 + P] * yr[L2*L2 + Q];
    EmitM<L1, L2, P*(2*L2+1)+Q, cgc::lminf(L1,L2), cgc::lmaxf(L1,L2), 0>::run(t, part);
    if constexpr (Q + 1 < 2*L2 + 1)
      PQLoop<L1,L2,P,Q+1>::run(xr, yr, part);
    else if constexpr (P + 1 < 2*L1 + 1)
      PQLoop<L1,L2,P+1,0>::run(xr, yr, part);
  }
};

template<int L1,int L2,int LO,int M>
struct ScaleM {
  static __device__ __forceinline__ void run(const float* __restrict__ part,
                                             float* __restrict__ acc, float fv){
    constexpr int s = LO*LO + M;
    constexpr bool touched = (cgc::firstPQv<L1,L2,LO>(M) != -1);
    if constexpr (cgc::isAccFirstOrd(L1,L2,LO)){
      if constexpr (touched) acc[s] = fv * part[cgc::poff(L1,L2,LO) + M];
      else                   acc[s] = 0.f;
    } else if constexpr (touched){
      acc[s] = fmaf(fv, part[cgc::poff(L1,L2,LO) + M], acc[s]);
    }
    if constexpr (M + 1 < 2*LO + 1) ScaleM<L1,L2,LO,M+1>::run(part, acc, fv);
  }
};

// f-values read LAZILY from LDS (ds_read_u16 per coupling) instead of a bulk
// 20-register fu block -- round-8's spill was exactly this 20-reg excess
// (live 140 > budget 128). LDS reads overlap VALU on the LGKM pipe.
template<int L1,int L2,int LO,int LMAX>
struct ScaleAccum {
  static __device__ __forceinline__ void run(const float* __restrict__ part,
                                             float* __restrict__ acc,
                                             const unsigned short* fB){
    const float fv = bf2f(fB[cgc::cplIndex(L1,L2,LO)]);
    ScaleM<L1,L2,LO,0>::run(part, acc, fv);
    if constexpr (LO < LMAX) ScaleAccum<L1,L2,LO+1,LMAX>::run(part, acc, fB);
  }
};

template<int L1,int L2>
__device__ __forceinline__ void computePart(const float* __restrict__ xr,
                                            const float* __restrict__ yr,
                                            float* __restrict__ part){
  PQLoop<L1,L2,0,0>::run(xr, yr, part);
}

template<int L1,int L2>
__device__ __forceinline__ void scalePart(const float* __restrict__ part,
                                          float* __restrict__ acc,
                                          const unsigned short* fB){
  ScaleAccum<L1,L2,cgc::lminf(L1,L2),cgc::lmaxf(L1,L2)>::run(part, acc, fB);
}

template<int L1,int L2>
__device__ __forceinline__ void doGroup(const float* __restrict__ xr,
                                        const float* __restrict__ yr,
                                        float* __restrict__ acc,
                                        const unsigned short* fB){
  float part[cgc::psize(L1,L2)];
  computePart<L1,L2>(xr, yr, part);
  scalePart<L1,L2>(part, acc, fB);
}

// ======================= kernels =======================
__global__ __launch_bounds__(256) void prep_wf(const float* __restrict__ W){
  const int idx = blockIdx.x*256 + threadIdx.x;         // 81920 total
  const int j = idx & 7;
  const int l = (idx >> 3) & 63;
  const int s = (idx >> 9) & 1;
  const int t = (idx >> 10) & 1;
  const int i = idx >> 11;
  const int k   = s*32 + ((l >> 4) << 3) + j;           // contiguous-8 k per lane
  const int col = (t << 4) + (l & 15);
  WF[idx] = f2bf(W[(i << 11) + (k << 5) + col]);
}

// Fm layout: n-major per edge row: u16 index = el*1280 + n*40 + i.
// Structure (round 7): diagonal groups' f-independent CG parts computed
// BEFORE the barrier (x/y loads get pre-barrier uses -> hoisted, MLP with
// phase-1 loads); off-diagonal groups after.
// waves_per_eu(4,4): VGPR budget 512/4 = 128.
// ROUND 9: lazy f reads (no 20-reg fu block). Liveness audit:
//   pre-barrier : 32 xy + 60 parts + ~10 temps       ~= 102
//   post-barrier: 32 xy + 60 parts + 25 acc + ~6 tmp ~= 123  <= 128, no spill
// (round 8 held fu too: 140 > 128 -> scratch. FETCH/WRITE are the signal.)
__global__ __launch_bounds__(512)
__attribute__((amdgpu_waves_per_eu(4,4)))
void pairmix(const float* __restrict__ x,
             const float* __restrict__ y,
             const float* __restrict__ r,
             float* __restrict__ out){
  __shared__ unsigned short Fm[16*1280];                // 40960 B
  const int e0   = blockIdx.x << 4;                     // 16 edges per block
  const int tid  = threadIdx.x;
  const int lane = tid & 63;
  const int wv   = tid >> 6;                            // 0..7

  // ---- x/y loads: issued first (oldest in vmcnt queue; phase-1's waits
  //      drain them for free while phase-1 stalls on its own loads) ----
  const int n  = tid & 31;
  const int el = tid >> 5;                              // 0..15
  const float* xp = x + (size_t)(e0 + el)*512 + n;
  const float* yp = y + (size_t)(e0 + el)*512 + n;
  float xr_[16], yr_[16];
  #pragma unroll
  for (int s = 0; s < 16; ++s){ xr_[s] = xp[s << 5]; yr_[s] = yp[s << 5]; }

  // ---- Phase 1: F = r @ W via bf16 MFMA (M=16 edges, N=1280, K=64) ----
  {
    const int mrow = lane & 15;                         // edge row
    const int kch  = (lane >> 4) << 3;                  // k chunk base
    const float* rp = r + (size_t)(e0 + mrow)*64 + kch;
    s8_t A[2];
    #pragma unroll
    for (int s = 0; s < 2; ++s){
      const float4 v0 = *(const float4*)(rp + s*32);
      const float4 v1 = *(const float4*)(rp + s*32 + 4);
      union { s8_t v; unsigned u[4]; } pk;
      pk.u[0] = (unsigned)f2bf(v0.x) | ((unsigned)f2bf(v0.y) << 16);
      pk.u[1] = (unsigned)f2bf(v0.z) | ((unsigned)f2bf(v0.w) << 16);
      pk.u[2] = (unsigned)f2bf(v1.x) | ((unsigned)f2bf(v1.y) << 16);
      pk.u[3] = (unsigned)f2bf(v1.z) | ((unsigned)f2bf(v1.w) << 16);
      A[s] = pk.v;
    }
    #pragma unroll
    for (int tt = 0; tt < 10; ++tt){                    // 8 waves x 10 = 80 tiles
      const int T  = wv*10 + tt;
      const int ci = T >> 1;                            // coupling 0..39
      const int th = T & 1;                             // n-half 0..1
      const s8_t B0 = *(const s8_t*)(WF + ((((ci*2 + th)*2 + 0)*64 + lane) << 3));
      const s8_t B1 = *(const s8_t*)(WF + ((((ci*2 + th)*2 + 1)*64 + lane) << 3));
      f4_t c = {0.f, 0.f, 0.f, 0.f};
      c = __builtin_amdgcn_mfma_f32_16x16x32_bf16(A[0], B0, c, 0, 0, 0);
      c = __builtin_amdgcn_mfma_f32_16x16x32_bf16(A[1], B1, c, 0, 0, 0);
      const int colN = th*16 + (lane & 15);             // channel n
      const int rb   = (lane >> 4) << 2;                // row-group base (edge)
      #pragma unroll
      for (int jj = 0; jj < 4; ++jj)
        Fm[(rb + jj)*1280 + colN*40 + ci] = f2bf(c[jj]); // C/D: col=lane&15, row=(lane>>4)*4+reg
    }
  }

  // ---- Pre-barrier: f-independent CG parts for the 4 diagonal groups ----
  float p00[cgc::psize(0,0)];   // 1
  float p11[cgc::psize(1,1)];   // 9
  float p22[cgc::psize(2,2)];   // 25
  float p33[cgc::psize(3,3)];   // 25
  computePart<0,0>(xr_, yr_, p00);
  computePart<1,1>(xr_, yr_, p11);
  computePart<2,2>(xr_, yr_, p22);
  computePart<3,3>(xr_, yr_, p33);

  __syncthreads();

  // ---- Post-barrier: lazy f reads + scaling + off-diagonal groups ----
  const unsigned short* fB = &Fm[el*1280 + n*40];

  float acc[25];                                        // first-touch-written per isAccFirstOrd

  scalePart<0,0>(p00, acc, fB);
  scalePart<1,1>(p11, acc, fB);
  scalePart<2,2>(p22, acc, fB);
  scalePart<3,3>(p33, acc, fB);

  doGroup<0,1>(xr_, yr_, acc, fB);
  doGroup<0,2>(xr_, yr_, acc, fB);
  doGroup<0,3>(xr_, yr_, acc, fB);
  doGroup<1,0>(xr_, yr_, acc, fB);
  doGroup<1,2>(xr_, yr_, acc, fB);
  doGroup<1,3>(xr_, yr_, acc, fB);
  doGroup<2,0>(xr_, yr_, acc, fB);
  doGroup<2,1>(xr_, yr_, acc, fB);
  doGroup<2,3>(xr_, yr_, acc, fB);
  doGroup<3,0>(xr_, yr_, acc, fB);
  doGroup<3,1>(xr_, yr_, acc, fB);
  doGroup<3,2>(xr_, yr_, acc, fB);

  float* op = out + (size_t)(e0 + el)*800 + n;
  #pragma unroll
  for (int s = 0; s < 25; ++s) op[s << 5] = acc[s];
}

// ======================= launch =======================
extern "C" void kernel_launch(void* const* d_in, const int* in_sizes, int n_in,
                              void* d_out, int out_size, void* d_ws, size_t ws_size,
                              hipStream_t stream){
  const float* x = (const float*)d_in[0];
  const float* y = (const float*)d_in[1];
  const float* r = (const float*)d_in[2];
  const float* W = (const float*)d_in[3];
  float* out = (float*)d_out;

  const int E = in_sizes[0] / 512;                      // 100000

  prep_wf<<<320, 256, 0, stream>>>(W);                  // 81920 threads
  pairmix<<<E / 16, 512, 0, stream>>>(x, y, r, out);
}

// Round 10
// 192.881 us; speedup vs baseline: 1.7873x; 1.0033x over previous
//
#include <hip/hip_runtime.h>

typedef short s8_t __attribute__((ext_vector_type(8)));
typedef float f4_t __attribute__((ext_vector_type(4)));

// ======================= compile-time Clebsch-Gordan =======================
namespace cgc {

struct Cx { double re, im; };

constexpr double FACT[13] = {1.,1.,2.,6.,24.,120.,720.,5040.,40320.,362880.,
                             3628800.,39916800.,479001600.};

constexpr double cfabs(double x){ return x < 0 ? -x : x; }

constexpr double csqrt(double x){
  if (x <= 0) return 0;
  double g = x > 1 ? x : 1.0;
  for (int i = 0; i < 80; ++i){
    double ng = 0.5*(g + x/g);
    if (ng == g) break;
    g = ng;
  }
  return g;
}

constexpr int imax3(int a,int b,int c){ int m=a; if(b>m)m=b; if(c>m)m=c; return m; }
constexpr int imin3(int a,int b,int c){ int m=a; if(b<m)m=b; if(c<m)m=c; return m; }

constexpr double clebsch(int j1,int m1,int j2,int m2,int j3,int m3){
  if (m1 + m2 != m3) return 0;
  const int jmin = j1 > j2 ? j1 - j2 : j2 - j1;
  if (j3 < jmin || j3 > j1 + j2) return 0;
  if (m1 < -j1 || m1 > j1 || m2 < -j2 || m2 > j2 || m3 < -j3 || m3 > j3) return 0;
  double pref = csqrt((2*j3+1)*FACT[j3+j1-j2]*FACT[j3-j1+j2]*FACT[j1+j2-j3]/FACT[j1+j2+j3+1]);
  pref *= csqrt(FACT[j3+m3]*FACT[j3-m3]*FACT[j1-m1]*FACT[j1+m1]*FACT[j2-m2]*FACT[j2+m2]);
  const int kmin = imax3(0, j2-j3-m1, j1-j3+m2);
  const int kmax = imin3(j1+j2-j3, j1-m1, j2+m2);
  double s = 0;
  for (int k = kmin; k <= kmax; ++k){
    double d = FACT[k]*FACT[j1+j2-j3-k]*FACT[j1-m1-k]*FACT[j2+m2-k]
             * FACT[j3-j2+m1+k]*FACT[j3-j1-m2+k];
    s += ((k & 1) ? -1.0 : 1.0) / d;
  }
  return pref * s;
}

constexpr Cx cmul(Cx a, Cx b){ return Cx{a.re*b.re - a.im*b.im, a.re*b.im + a.im*b.re}; }

// U[l+mr][l+mc] of the complex->real SH transform (row: real m, col: complex m)
constexpr Cx Uc2r(int mr, int mc){
  const double s2i = 0.70710678118654752440;
  if (mr == 0) return (mc == 0) ? Cx{1.,0.} : Cx{0.,0.};
  if (mr > 0){
    if (mc ==  mr) return Cx{ (mr & 1) ? -s2i : s2i, 0. };
    if (mc == -mr) return Cx{ s2i, 0. };
    return Cx{0.,0.};
  }
  const int m = -mr;
  if (mc ==  m) return Cx{0., (m & 1) ?  s2i : -s2i };
  if (mc == -m) return Cx{0., s2i };
  return Cx{0.,0.};
}

template<int L1,int L2,int L3>
struct CArr { float v[(2*L1+1)*(2*L2+1)*(2*L3+1)]; };

template<int L1,int L2,int L3>
constexpr CArr<L1,L2,L3> buildCG(){
  constexpr int D1 = 2*L1+1, D2 = 2*L2+1, D3 = 2*L3+1;
  // complex-basis CG cached once per coupling (m3 = m1+m2 enforced)
  double cgd[D1*D2] = {};
  for (int i = 0; i < D1; ++i)
    for (int j = 0; j < D2; ++j){
      const int m1c = i - L1, m2c = j - L2, m3c = m1c + m2c;
      cgd[i*D2+j] = (m3c < -L3 || m3c > L3) ? 0.0 : clebsch(L1,m1c,L2,m2c,L3,m3c);
    }
  double tre[D1*D2*D3] = {};
  double tim[D1*D2*D3] = {};
  for (int a = 0; a < D1; ++a)
  for (int b = 0; b < D2; ++b)
  for (int c = 0; c < D3; ++c){
    const int m1r = a - L1, m2r = b - L2, m3r = c - L3;
    double sre = 0, sim = 0;
    const int n1 = (m1r == 0) ? 1 : 2;
    const int n2 = (m2r == 0) ? 1 : 2;
    for (int ii = 0; ii < n1; ++ii)
    for (int jj = 0; jj < n2; ++jj){
      const int m1c = ii ? -m1r : m1r;
      const int m2c = jj ? -m2r : m2r;
      const int m3c = m1c + m2c;
      if (m3c < -L3 || m3c > L3) continue;
      const Cx u3 = Uc2r(m3r, m3c);
      if (u3.re == 0 && u3.im == 0) continue;
      const double cgv = cgd[(L1+m1c)*D2 + (L2+m2c)];
      if (cgv == 0) continue;
      const Cx u1 = Uc2r(m1r, m1c);
      const Cx u2 = Uc2r(m2r, m2c);
      const Cx p  = cmul(u1, u2);
      const Cx t  = cmul(p, Cx{u3.re, -u3.im});   // conj(U3)
      sre += t.re * cgv;
      sim += t.im * cgv;
    }
    tre[(a*D2+b)*D3+c] = sre;
    tim[(a*D2+b)*D3+c] = sim;
  }
  // tensor is purely real or purely imaginary; pick like the reference
  double mre = 0, mim = 0;
  for (int k = 0; k < D1*D2*D3; ++k){
    if (cfabs(tre[k]) > mre) mre = cfabs(tre[k]);
    if (cfabs(tim[k]) > mim) mim = cfabs(tim[k]);
  }
  CArr<L1,L2,L3> o{};
  for (int k = 0; k < D1*D2*D3; ++k)
    o.v[k] = (float)((mre >= mim) ? tre[k] : tim[k]);
  return o;
}

template<int L1,int L2,int L3>
constexpr CArr<L1,L2,L3> CG_V = buildCG<L1,L2,L3>();

constexpr int lminf(int a,int b){ return a > b ? a - b : b - a; }
constexpr int lmaxf(int a,int b){ return (a + b < 4) ? (a + b) : 4; }
constexpr int cplIndex(int l1,int l2,int lo){
  int idx = 0;
  for (int a = 0; a <= 3; ++a)
    for (int b = 0; b <= 3; ++b){
      const int c0 = lminf(a,b), c1 = lmaxf(a,b);
      for (int c = c0; c <= c1; ++c){
        if (a == l1 && b == l2 && c == lo) return idx;
        ++idx;
      }
    }
  return -1;
}
constexpr int poff(int l1,int l2,int lo){
  int s = 0;
  for (int c = lminf(l1,l2); c < lo; ++c) s += 2*c + 1;
  return s;
}
constexpr int psize(int l1,int l2){ return poff(l1, l2, lmaxf(l1,l2) + 1); }

// first pq index (in P-major execution order) whose cg for slot (LO,M) is
// nonzero -> that FMA becomes a plain mul (kills the part[] zero-init movs)
template<int L1,int L2,int LO>
constexpr int firstPQv(int M){
  const int NPQ = (2*L1+1)*(2*L2+1);
  for (int pq = 0; pq < NPQ; ++pq){
    const float v = CG_V<L1,L2,LO>.v[pq*(2*LO+1)+M];
    if (v > 1e-7f || v < -1e-7f) return pq;
  }
  return -1;
}

// EXECUTION ORDER of the 16 (l1,l2) groups: diagonal first, then off-diagonal.
// acc[] first-touch logic MUST follow this order.
constexpr int ORD_L1[16] = {0,1,2,3, 0,0,0, 1,1,1, 2,2,2, 3,3,3};
constexpr int ORD_L2[16] = {0,1,2,3, 1,2,3, 0,2,3, 0,1,3, 0,1,2};

// is (l1,l2) the FIRST group in execution order that couples into lo?
constexpr bool isAccFirstOrd(int l1,int l2,int lo){
  for (int k = 0; k < 16; ++k){
    const int a = ORD_L1[k], b = ORD_L2[k];
    if (lminf(a,b) <= lo && lo <= lmaxf(a,b))
      return (a == l1) && (b == l2);
  }
  return false;
}

} // namespace cgc

// ======================= device helpers =======================
__device__ __forceinline__ unsigned short f2bf(float x){
  unsigned u = __float_as_uint(x);
  u += 0x7fffu + ((u >> 16) & 1u);       // RNE
  return (unsigned short)(u >> 16);
}
__device__ __forceinline__ float bf2f(unsigned short h){
  return __uint_as_float(((unsigned)h) << 16);
}

// Opaque global load: asm volatile cannot be sunk/deleted/reordered (among
// volatiles) by the compiler -- this is what rounds 4-6/9 were missing. The
// load issues where written; its result reg is live from here on. NOTE: the
// compiler does NOT know this is a load, so we must s_waitcnt vmcnt manually
// before first use (see tie_after_wait).
__device__ __forceinline__ float gload(const float* p){
  float d;
  asm volatile("global_load_dword %0, %1, off"
               : "=v"(d)
               : "v"((unsigned long long)(size_t)p));
  return d;
}

// W pre-packed into bf16 MFMA B-fragment order: [i][ntile][kstep][lane][8]
__device__ __attribute__((aligned(16))) unsigned short WF[81920];

// ---- CG accumulation: ALL indices template params -> literal coefficients,
// zeros deleted, first touch per slot is a write (no zero-init). ----
template<int L1,int L2,int PQ,int LO,int LMAX,int M>
struct EmitM {
  static __device__ __forceinline__ void run(float t, float* __restrict__ part){
    constexpr float cg = cgc::CG_V<L1,L2,LO>.v[PQ*(2*LO+1) + M];
    if constexpr (cg > 1e-7f || cg < -1e-7f){
      constexpr int off = cgc::poff(L1,L2,LO) + M;
      if constexpr (PQ == cgc::firstPQv<L1,L2,LO>(M))
        part[off] = cg * t;
      else
        part[off] = fmaf(cg, t, part[off]);
    }
    if constexpr (M + 1 < 2*LO + 1)
      EmitM<L1,L2,PQ,LO,LMAX,M+1>::run(t, part);
    else if constexpr (LO < LMAX)
      EmitM<L1,L2,PQ,LO+1,LMAX,0>::run(t, part);
  }
};

template<int L1,int L2,int P,int Q>
struct PQLoop {
  static __device__ __forceinline__ void run(const float* __restrict__ xr,
                                             const float* __restrict__ yr,
                                             float* __restrict__ part){
    const float t = xr[L1*L1 + P] * yr[L2*L2 + Q];
    EmitM<L1, L2, P*(2*L2+1)+Q, cgc::lminf(L1,L2), cgc::lmaxf(L1,L2), 0>::run(t, part);
    if constexpr (Q + 1 < 2*L2 + 1)
      PQLoop<L1,L2,P,Q+1>::run(xr, yr, part);
    else if constexpr (P + 1 < 2*L1 + 1)
      PQLoop<L1,L2,P+1,0>::run(xr, yr, part);
  }
};

template<int L1,int L2,int LO,int M>
struct ScaleM {
  static __device__ __forceinline__ void run(const float* __restrict__ part,
                                             float* __restrict__ acc, float fv){
    constexpr int s = LO*LO + M;
    constexpr bool touched = (cgc::firstPQv<L1,L2,LO>(M) != -1);
    if constexpr (cgc::isAccFirstOrd(L1,L2,LO)){
      if constexpr (touched) acc[s] = fv * part[cgc::poff(L1,L2,LO) + M];
      else                   acc[s] = 0.f;
    } else if constexpr (touched){
      acc[s] = fmaf(fv, part[cgc::poff(L1,L2,LO) + M], acc[s]);
    }
    if constexpr (M + 1 < 2*LO + 1) ScaleM<L1,L2,LO,M+1>::run(part, acc, fv);
  }
};

// f-values read LAZILY from LDS (ds_read_u16 per coupling): no bulk register
// block (round-8's spill source). LDS reads overlap VALU on the LGKM pipe.
template<int L1,int L2,int LO,int LMAX>
struct ScaleAccum {
  static __device__ __forceinline__ void run(const float* __restrict__ part,
                                             float* __restrict__ acc,
                                             const unsigned short* fB){
    const float fv = bf2f(fB[cgc::cplIndex(L1,L2,LO)]);
    ScaleM<L1,L2,LO,0>::run(part, acc, fv);
    if constexpr (LO < LMAX) ScaleAccum<L1,L2,LO+1,LMAX>::run(part, acc, fB);
  }
};

template<int L1,int L2>
__device__ __forceinline__ void doGroup(const float* __restrict__ xr,
                                        const float* __restrict__ yr,
                                        float* __restrict__ acc,
                                        const unsigned short* fB){
  float part[cgc::psize(L1,L2)];
  PQLoop<L1,L2,0,0>::run(xr, yr, part);
  ScaleAccum<L1,L2,cgc::lminf(L1,L2),cgc::lmaxf(L1,L2)>::run(part, acc, fB);
}

// ======================= kernels =======================
__global__ __launch_bounds__(256) void prep_wf(const float* __restrict__ W){
  const int idx = blockIdx.x*256 + threadIdx.x;         // 81920 total
  const int j = idx & 7;
  const int l = (idx >> 3) & 63;
  const int s = (idx >> 9) & 1;
  const int t = (idx >> 10) & 1;
  const int i = idx >> 11;
  const int k   = s*32 + ((l >> 4) << 3) + j;           // contiguous-8 k per lane
  const int col = (t << 4) + (l & 15);
  WF[idx] = f2bf(W[(i << 11) + (k << 5) + col]);
}

// Fm layout: n-major per edge row: u16 index = el*1280 + n*40 + i.
//
// ROUND 10: x/y prefetched via OPAQUE asm-volatile global_load_dword at the
// top of the kernel. The compiler cannot sink asm volatiles (rounds 4-6/9:
// every visible-load variant was sunk back to phase-2 start, VGPR 56-64,
// latency exposed). The 64 loads sit oldest in the vmcnt queue, so phase-1's
// own waits + the barrier drain retire them UNDER phase-1 compute -- x/y HBM
// latency merges with phase-1's r/WF latency instead of serializing.
// After the barrier: explicit s_waitcnt vmcnt(0) (volatile => ordered after
// the load asms) + value-tying asms so no use schedules before the wait
// (rule-#18 hazard: register-only consumers can hoist past a bare waitcnt).
// Phase 2 runs one group at a time (ORD order == isAccFirstOrd order):
// peak live ~= 64 prefetch + 25 acc + 25 part + temps ~= 120 <= 128 budget
// from waves_per_eu(4,4).
__global__ __launch_bounds__(512)
__attribute__((amdgpu_waves_per_eu(4,4)))
void pairmix(const float* __restrict__ x,
             const float* __restrict__ y,
             const float* __restrict__ r,
             float* __restrict__ out){
  __shared__ unsigned short Fm[16*1280];                // 40960 B
  const int e0   = blockIdx.x << 4;                     // 16 edges per block
  const int tid  = threadIdx.x;
  const int lane = tid & 63;
  const int wv   = tid >> 6;                            // 0..7

  // ---- Opaque x/y prefetch: issued HERE, in flight through phase 1 ----
  const int n  = tid & 31;
  const int el = tid >> 5;                              // 0..15
  const float* xp = x + (size_t)(e0 + el)*512 + n;
  const float* yp = y + (size_t)(e0 + el)*512 + n;
  float xr_[16], yr_[16];
  #pragma unroll
  for (int s = 0; s < 16; ++s){
    xr_[s] = gload(xp + (s << 5));
    yr_[s] = gload(yp + (s << 5));
  }

  // ---- Phase 1: F = r @ W via bf16 MFMA (M=16 edges, N=1280, K=64) ----
  {
    const int mrow = lane & 15;                         // edge row
    const int kch  = (lane >> 4) << 3;                  // k chunk base
    const float* rp = r + (size_t)(e0 + mrow)*64 + kch;
    s8_t A[2];
    #pragma unroll
    for (int s = 0; s < 2; ++s){
      const float4 v0 = *(const float4*)(rp + s*32);
      const float4 v1 = *(const float4*)(rp + s*32 + 4);
      union { s8_t v; unsigned u[4]; } pk;
      pk.u[0] = (unsigned)f2bf(v0.x) | ((unsigned)f2bf(v0.y) << 16);
      pk.u[1] = (unsigned)f2bf(v0.z) | ((unsigned)f2bf(v0.w) << 16);
      pk.u[2] = (unsigned)f2bf(v1.x) | ((unsigned)f2bf(v1.y) << 16);
      pk.u[3] = (unsigned)f2bf(v1.z) | ((unsigned)f2bf(v1.w) << 16);
      A[s] = pk.v;
    }
    #pragma unroll
    for (int tt = 0; tt < 10; ++tt){                    // 8 waves x 10 = 80 tiles
      const int T  = wv*10 + tt;
      const int ci = T >> 1;                            // coupling 0..39
      const int th = T & 1;                             // n-half 0..1
      const s8_t B0 = *(const s8_t*)(WF + ((((ci*2 + th)*2 + 0)*64 + lane) << 3));
      const s8_t B1 = *(const s8_t*)(WF + ((((ci*2 + th)*2 + 1)*64 + lane) << 3));
      f4_t c = {0.f, 0.f, 0.f, 0.f};
      c = __builtin_amdgcn_mfma_f32_16x16x32_bf16(A[0], B0, c, 0, 0, 0);
      c = __builtin_amdgcn_mfma_f32_16x16x32_bf16(A[1], B1, c, 0, 0, 0);
      const int colN = th*16 + (lane & 15);             // channel n
      const int rb   = (lane >> 4) << 2;                // row-group base (edge)
      #pragma unroll
      for (int jj = 0; jj < 4; ++jj)
        Fm[(rb + jj)*1280 + colN*40 + ci] = f2bf(c[jj]); // C/D: col=lane&15, row=(lane>>4)*4+reg
    }
  }

  __syncthreads();

  // ---- Drain the prefetch (ordered after the load asms by volatility),
  //      then tie every value so no use can hoist above the wait ----
  asm volatile("s_waitcnt vmcnt(0)");
  #pragma unroll
  for (int s = 0; s < 16; s += 4)
    asm volatile("" : "+v"(xr_[s]), "+v"(xr_[s+1]), "+v"(xr_[s+2]), "+v"(xr_[s+3]),
                      "+v"(yr_[s]), "+v"(yr_[s+1]), "+v"(yr_[s+2]), "+v"(yr_[s+3]));

  // ---- Phase 2: CG contraction, one group at a time (ORD order) ----
  const unsigned short* fB = &Fm[el*1280 + n*40];
  float acc[25];                                        // first-touch per isAccFirstOrd

  doGroup<0,0>(xr_, yr_, acc, fB);
  doGroup<1,1>(xr_, yr_, acc, fB);
  doGroup<2,2>(xr_, yr_, acc, fB);
  doGroup<3,3>(xr_, yr_, acc, fB);
  doGroup<0,1>(xr_, yr_, acc, fB);
  doGroup<0,2>(xr_, yr_, acc, fB);
  doGroup<0,3>(xr_, yr_, acc, fB);
  doGroup<1,0>(xr_, yr_, acc, fB);
  doGroup<1,2>(xr_, yr_, acc, fB);
  doGroup<1,3>(xr_, yr_, acc, fB);
  doGroup<2,0>(xr_, yr_, acc, fB);
  doGroup<2,1>(xr_, yr_, acc, fB);
  doGroup<2,3>(xr_, yr_, acc, fB);
  doGroup<3,0>(xr_, yr_, acc, fB);
  doGroup<3,1>(xr_, yr_, acc, fB);
  doGroup<3,2>(xr_, yr_, acc, fB);

  float* op = out + (size_t)(e0 + el)*800 + n;
  #pragma unroll
  for (int s = 0; s < 25; ++s) op[s << 5] = acc[s];
}

// ======================= launch =======================
extern "C" void kernel_launch(void* const* d_in, const int* in_sizes, int n_in,
                              void* d_out, int out_size, void* d_ws, size_t ws_size,
                              hipStream_t stream){
  const float* x = (const float*)d_in[0];
  const float* y = (const float*)d_in[1];
  const float* r = (const float*)d_in[2];
  const float* W = (const float*)d_in[3];
  float* out = (float*)d_out;

  const int E = in_sizes[0] / 512;                      // 100000

  prep_wf<<<320, 256, 0, stream>>>(W);                  // 81920 threads
  pairmix<<<E / 16, 512, 0, stream>>>(x, y, r, out);
}